// Round 20
// baseline (202.002 us; speedup 1.0000x reference)
//
#include <hip/hip_runtime.h>

#define HH 192
#define WW 256
#define NPIX (HH*WW)   // 49152
#define NSEG (NPIX/64) // 768

__device__ __forceinline__ float lrelu(float v) { return v > 0.0f ? v : 0.01f * v; }

// bf16 hi/lo split helpers (RNE via round-half-up on guard bit)
__device__ __forceinline__ unsigned short bfhi(float x) {
    unsigned b = __float_as_uint(x);
    return (unsigned short)((b + 0x7FFFu + ((b >> 16) & 1u)) >> 16);
}
__device__ __forceinline__ float bff(unsigned short u) {
    return __uint_as_float(((unsigned)u) << 16);
}

typedef __attribute__((ext_vector_type(8))) short short8v;  // 8 bf16 = 4 VGPR
typedef __attribute__((ext_vector_type(4))) short short4v;  // 8B packed write
typedef __attribute__((ext_vector_type(4))) float f32x4;    // MFMA acc

// ============================================================================
// k_fused1 (R26): y=0 now computes BOTH x_t (4-term) and r_t (3-term) from a
// SINGLE X staging pass (X read 2x not 3x; bf16 conversion VALU halved for
// the pair). Safe now because MFMA accs live in AGPRs (R25 counters: 72 VGPR
// with 64-elem acc) — 128 AGPR + ~72 VGPR fits at 2 blocks/CU, LDS 60KB.
// Arithmetic bit-identical to R25 -> absmax must stay 2.441406e-4.
// y=1: mask branch (R23/R24 verified text).
// Spill alarm: WRITE ballooning -> revert to R25.
// ============================================================================
__global__ __launch_bounds__(256, 2) void k_fused1(
    const float* __restrict__ X,
    const float* __restrict__ Wcl1, const float* __restrict__ bcl1,
    const float* __restrict__ Wr1,  const float* __restrict__ br1,
    const float* __restrict__ Wm1,  const float* __restrict__ bm1,
    const float* __restrict__ Wm2,  const float* __restrict__ bm2,
    const float* __restrict__ Wm3,  const float* __restrict__ bm3,
    float* __restrict__ x_t, float* __restrict__ r_t,
    float* __restrict__ out)
{
    __shared__ unsigned short smem_us[30720];          // 61440 B max (merged)

    const int tid = threadIdx.x;
    const int q0  = blockIdx.x * 128;

    if (blockIdx.y == 1) {
        // ---- mask branch (R23/R24 verified text) ----
        unsigned short* Wmhi = smem_us;                        // [32][40]
        unsigned short* Wmlo = Wmhi + 1280;                    // [32][40]
        unsigned short* Xthi = Wmlo + 1280;                    // [128][40]
        unsigned short* Xtlo = Xthi + 5120;                    // [128][40]
        float (*m1b)[33] = (float(*)[33])smem_us;              // post-loop alias

        const int l = tid & 63;
        const int w = tid >> 6;
        const int c = l & 15;
        const int g = l >> 4;

        float bvm[2][4];
        #pragma unroll
        for (int ot = 0; ot < 2; ++ot)
            #pragma unroll
            for (int r = 0; r < 4; ++r)
                bvm[ot][r] = bm1[ot * 16 + g * 4 + r];

        f32x4 accM[2][2];
        #pragma unroll
        for (int ot = 0; ot < 2; ++ot)
            #pragma unroll
            for (int pi = 0; pi < 2; ++pi) {
                accM[ot][pi][0] = bvm[ot][0]; accM[ot][pi][1] = bvm[ot][1];
                accM[ot][pi][2] = bvm[ot][2]; accM[ot][pi][3] = bvm[ot][3];
            }

        const int sx_px = tid & 127;
        const int sx_kh = (tid >> 7) * 16;
        const float* Xp = X + q0 + sx_px;

        for (int k0 = 0; k0 < 128; k0 += 32) {
            {
                float xv[16];
                #pragma unroll
                for (int i = 0; i < 16; ++i)
                    xv[i] = Xp[(size_t)(k0 + sx_kh + i) * NPIX];
                #pragma unroll
                for (int j = 0; j < 2; ++j) {
                    short8v hv, lv;
                    #pragma unroll
                    for (int i = 0; i < 8; ++i) {
                        unsigned short h = bfhi(xv[j * 8 + i]);
                        hv[i] = (short)h;
                        lv[i] = (short)bfhi(xv[j * 8 + i] - bff(h));
                    }
                    int gg = (sx_kh >> 3) + j;
                    int gs = gg ^ ((sx_px >> 3) & 3);
                    *(short8v*)(Xthi + sx_px * 40 + gs * 8) = hv;
                    *(short8v*)(Xtlo + sx_px * 40 + gs * 8) = lv;
                }
            }
            {
                int o = tid >> 3, kc = (tid & 7) * 4;
                float4 v = *(const float4*)(Wm1 + o * 128 + k0 + kc);
                float wv[4] = {v.x, v.y, v.z, v.w};
                short4v hv, lv;
                #pragma unroll
                for (int i = 0; i < 4; ++i) {
                    unsigned short h = bfhi(wv[i]);
                    hv[i] = (short)h;
                    lv[i] = (short)bfhi(wv[i] - bff(h));
                }
                int gg = kc >> 3;
                int gs = gg ^ (o & 3);
                int addr = o * 40 + gs * 8 + (kc & 7);
                *(short4v*)(Wmhi + addr) = hv;
                *(short4v*)(Wmlo + addr) = lv;
            }
            __syncthreads();

            short8v ahi[2], alo[2];
            #pragma unroll
            for (int ot = 0; ot < 2; ++ot) {
                int row = ot * 16 + c;
                int ao = row * 40 + (g ^ (row & 3)) * 8;
                ahi[ot] = *(const short8v*)(Wmhi + ao);
                alo[ot] = *(const short8v*)(Wmlo + ao);
            }
            #pragma unroll
            for (int pi = 0; pi < 2; ++pi) {
                int row = (2 * w + pi) * 16 + c;
                int bo = row * 40 + (g ^ ((row >> 3) & 3)) * 8;
                short8v bhi = *(const short8v*)(Xthi + bo);
                short8v blo = *(const short8v*)(Xtlo + bo);
                #pragma unroll
                for (int ot = 0; ot < 2; ++ot) {
                    accM[ot][pi] = __builtin_amdgcn_mfma_f32_16x16x32_bf16(
                        ahi[ot], bhi, accM[ot][pi], 0, 0, 0);
                    accM[ot][pi] = __builtin_amdgcn_mfma_f32_16x16x32_bf16(
                        ahi[ot], blo, accM[ot][pi], 0, 0, 0);
                    accM[ot][pi] = __builtin_amdgcn_mfma_f32_16x16x32_bf16(
                        alo[ot], bhi, accM[ot][pi], 0, 0, 0);
                }
            }
            __syncthreads();
        }
        #pragma unroll
        for (int pi = 0; pi < 2; ++pi) {
            int px = (2 * w + pi) * 16 + c;
            #pragma unroll
            for (int ot = 0; ot < 2; ++ot)
                #pragma unroll
                for (int r = 0; r < 4; ++r)
                    m1b[px][ot * 16 + g * 4 + r] = lrelu(accM[ot][pi][r]);
        }
        __syncthreads();
        if (tid < 128) {
            float m3 = bm3[0];
            #pragma unroll 2
            for (int j = 0; j < 16; ++j) {
                float s = bm2[j];
                #pragma unroll
                for (int k = 0; k < 32; ++k)
                    s = fmaf(Wm2[j * 32 + k], m1b[tid][k], s);
                m3 = fmaf(Wm3[j], lrelu(s), m3);
            }
            out[NPIX + q0 + tid] = lrelu(m3);
        }
        return;
    }

    // ---- y=0 MERGED: x_t (4-term) + r_t (3-term), single X staging ----
    {
        unsigned short* WAhi = smem_us;                // Wcl1 [128][40]
        unsigned short* WAlo = WAhi + 5120;
        unsigned short* WBhi = WAlo + 5120;            // Wr1 [128][40]
        unsigned short* WBlo = WBhi + 5120;
        unsigned short* Xthi = WBlo + 5120;            // [128px][40]
        unsigned short* Xtlo = Xthi + 5120;

        const int l = tid & 63;
        const int w = tid >> 6;
        const int c = l & 15;
        const int g = l >> 4;
        const int o0 = w * 32;

        f32x4 accA[2][8], accB[2][8];
        #pragma unroll
        for (int ot = 0; ot < 2; ++ot) {
            #pragma unroll
            for (int r = 0; r < 4; ++r) {
                float ba = bcl1[o0 + ot * 16 + g * 4 + r];
                float bb = br1 [o0 + ot * 16 + g * 4 + r];
                #pragma unroll
                for (int pt = 0; pt < 8; ++pt) {
                    accA[ot][pt][r] = ba;
                    accB[ot][pt][r] = bb;
                }
            }
        }

        const int sx_px = tid & 127;
        const int sx_kh = (tid >> 7) * 16;
        const float* Xp = X + q0 + sx_px;

        for (int k0 = 0; k0 < 128; k0 += 32) {
            // stage X once (verified pattern)
            {
                float xv[16];
                #pragma unroll
                for (int i = 0; i < 16; ++i)
                    xv[i] = Xp[(size_t)(k0 + sx_kh + i) * NPIX];
                #pragma unroll
                for (int j = 0; j < 2; ++j) {
                    short8v hv, lv;
                    #pragma unroll
                    for (int i = 0; i < 8; ++i) {
                        unsigned short h = bfhi(xv[j * 8 + i]);
                        hv[i] = (short)h;
                        lv[i] = (short)bfhi(xv[j * 8 + i] - bff(h));
                    }
                    int gg = (sx_kh >> 3) + j;
                    int gs = gg ^ ((sx_px >> 3) & 3);
                    *(short8v*)(Xthi + sx_px * 40 + gs * 8) = hv;
                    *(short8v*)(Xtlo + sx_px * 40 + gs * 8) = lv;
                }
            }
            // stage Wcl1 + Wr1 tiles (verified pattern, two targets)
            #pragma unroll
            for (int p = 0; p < 4; ++p) {
                int lin = p * 1024 + tid * 4;
                int o = lin >> 5, kc = lin & 31;
                int gg = kc >> 3;
                int gs = gg ^ (o & 3);
                int addr = o * 40 + gs * 8 + (kc & 7);
                {
                    float4 v = *(const float4*)(Wcl1 + o * 128 + k0 + kc);
                    float wv[4] = {v.x, v.y, v.z, v.w};
                    short4v hv, lv;
                    #pragma unroll
                    for (int i = 0; i < 4; ++i) {
                        unsigned short h = bfhi(wv[i]);
                        hv[i] = (short)h;
                        lv[i] = (short)bfhi(wv[i] - bff(h));
                    }
                    *(short4v*)(WAhi + addr) = hv;
                    *(short4v*)(WAlo + addr) = lv;
                }
                {
                    float4 v = *(const float4*)(Wr1 + o * 128 + k0 + kc);
                    float wv[4] = {v.x, v.y, v.z, v.w};
                    short4v hv, lv;
                    #pragma unroll
                    for (int i = 0; i < 4; ++i) {
                        unsigned short h = bfhi(wv[i]);
                        hv[i] = (short)h;
                        lv[i] = (short)bfhi(wv[i] - bff(h));
                    }
                    *(short4v*)(WBhi + addr) = hv;
                    *(short4v*)(WBlo + addr) = lv;
                }
            }
            __syncthreads();

            short8v aAhi[2], aAlo[2], aBhi[2], aBlo[2];
            #pragma unroll
            for (int ot = 0; ot < 2; ++ot) {
                int row = o0 + ot * 16 + c;
                int ao = row * 40 + (g ^ (row & 3)) * 8;
                aAhi[ot] = *(const short8v*)(WAhi + ao);
                aAlo[ot] = *(const short8v*)(WAlo + ao);
                aBhi[ot] = *(const short8v*)(WBhi + ao);
                aBlo[ot] = *(const short8v*)(WBlo + ao);
            }
            #pragma unroll
            for (int pt = 0; pt < 8; ++pt) {
                int row = pt * 16 + c;
                int bo = row * 40 + (g ^ ((row >> 3) & 3)) * 8;
                short8v bhi = *(const short8v*)(Xthi + bo);
                short8v blo = *(const short8v*)(Xtlo + bo);
                #pragma unroll
                for (int ot = 0; ot < 2; ++ot) {
                    // x_t: 4-term
                    accA[ot][pt] = __builtin_amdgcn_mfma_f32_16x16x32_bf16(
                        aAhi[ot], bhi, accA[ot][pt], 0, 0, 0);
                    accA[ot][pt] = __builtin_amdgcn_mfma_f32_16x16x32_bf16(
                        aAhi[ot], blo, accA[ot][pt], 0, 0, 0);
                    accA[ot][pt] = __builtin_amdgcn_mfma_f32_16x16x32_bf16(
                        aAlo[ot], bhi, accA[ot][pt], 0, 0, 0);
                    accA[ot][pt] = __builtin_amdgcn_mfma_f32_16x16x32_bf16(
                        aAlo[ot], blo, accA[ot][pt], 0, 0, 0);
                    // r_t: 3-term
                    accB[ot][pt] = __builtin_amdgcn_mfma_f32_16x16x32_bf16(
                        aBhi[ot], bhi, accB[ot][pt], 0, 0, 0);
                    accB[ot][pt] = __builtin_amdgcn_mfma_f32_16x16x32_bf16(
                        aBhi[ot], blo, accB[ot][pt], 0, 0, 0);
                    accB[ot][pt] = __builtin_amdgcn_mfma_f32_16x16x32_bf16(
                        aBlo[ot], bhi, accB[ot][pt], 0, 0, 0);
                }
            }
            __syncthreads();
        }

        #pragma unroll
        for (int pt = 0; pt < 8; ++pt) {
            int px = pt * 16 + c;
            int q  = q0 + px;
            int np = (q & 255) * 192 + (q >> 8);
            float* opA = x_t + (size_t)np * 128;
            float* opB = r_t + (size_t)np * 128;
            #pragma unroll
            for (int ot = 0; ot < 2; ++ot) {
                float4 oa, ob;
                oa.x = lrelu(accA[ot][pt][0]); oa.y = lrelu(accA[ot][pt][1]);
                oa.z = lrelu(accA[ot][pt][2]); oa.w = lrelu(accA[ot][pt][3]);
                ob.x = lrelu(accB[ot][pt][0]); ob.y = lrelu(accB[ot][pt][1]);
                ob.z = lrelu(accB[ot][pt][2]); ob.w = lrelu(accB[ot][pt][3]);
                *(float4*)(opA + o0 + ot * 16 + g * 4) = oa;
                *(float4*)(opB + o0 + ot * 16 + g * 4) = ob;
            }
        }
    }
}

// ============================================================================
// k1b (R25 text, verified): 4-term MFMA GEMM + fp32 B-phase, PX=64.
// ============================================================================
__global__ __launch_bounds__(256, 3) void k1b(
    const float* __restrict__ x_t,
    const float* __restrict__ Wcl21, const float* __restrict__ bcl21,
    const float* __restrict__ Wcl31, const float* __restrict__ bcl31,
    int* __restrict__ inds1_q)
{
    __shared__ float smem[12928];                       // 51712 B
    unsigned short* Whi  = (unsigned short*)smem;       // [128][40]
    unsigned short* Wlo  = Whi + 5120;                  // [128][40]
    unsigned short* Xthi = Wlo + 5120;                  // [64][40]
    unsigned short* Xtlo = Xthi + 2560;                 // [64][40]
    float (*x2t)[68]    = (float(*)[68])smem;           // [128][68]
    float (*W31)[132]   = (float(*)[132])(smem + 8704); // [32][132]
    float (*cl1buf)[33] = (float(*)[33])(smem + 8704);  // aliases W31

    const int tid = threadIdx.x;
    const int n0  = blockIdx.x * 64;
    const int l = tid & 63, w = tid >> 6;
    const int c = l & 15, g = l >> 4;
    const int o0 = w * 32;

    float bv[2][4];
    #pragma unroll
    for (int ot = 0; ot < 2; ++ot)
        #pragma unroll
        for (int r = 0; r < 4; ++r)
            bv[ot][r] = bcl21[o0 + ot * 16 + g * 4 + r];

    f32x4 acc[2][4];
    #pragma unroll
    for (int ot = 0; ot < 2; ++ot)
        #pragma unroll
        for (int pt = 0; pt < 4; ++pt) {
            acc[ot][pt][0] = bv[ot][0]; acc[ot][pt][1] = bv[ot][1];
            acc[ot][pt][2] = bv[ot][2]; acc[ot][pt][3] = bv[ot][3];
        }

    const int sx_px = tid & 63;
    const int sx_kh = (tid >> 6) * 8;
    const float* Xp = x_t + (size_t)(n0 + sx_px) * 128 + sx_kh;

    for (int k0 = 0; k0 < 128; k0 += 32) {
        {
            float4 v0 = *(const float4*)(Xp + k0);
            float4 v1 = *(const float4*)(Xp + k0 + 4);
            float xv[8] = {v0.x,v0.y,v0.z,v0.w,v1.x,v1.y,v1.z,v1.w};
            short8v hv, lv;
            #pragma unroll
            for (int i = 0; i < 8; ++i) {
                unsigned short h = bfhi(xv[i]);
                hv[i] = (short)h;
                lv[i] = (short)bfhi(xv[i] - bff(h));
            }
            int gg = sx_kh >> 3;
            int gs = gg ^ ((sx_px >> 3) & 3);
            *(short8v*)(Xthi + sx_px * 40 + gs * 8) = hv;
            *(short8v*)(Xtlo + sx_px * 40 + gs * 8) = lv;
        }
        #pragma unroll
        for (int p = 0; p < 4; ++p) {
            int lin = p * 1024 + tid * 4;
            int o = lin >> 5, kc = lin & 31;
            float4 v = *(const float4*)(Wcl21 + o * 128 + k0 + kc);
            float wv[4] = {v.x, v.y, v.z, v.w};
            short4v hv, lv;
            #pragma unroll
            for (int i = 0; i < 4; ++i) {
                unsigned short h = bfhi(wv[i]);
                hv[i] = (short)h;
                lv[i] = (short)bfhi(wv[i] - bff(h));
            }
            int gg = kc >> 3;
            int gs = gg ^ (o & 3);
            int addr = o * 40 + gs * 8 + (kc & 7);
            *(short4v*)(Whi + addr) = hv;
            *(short4v*)(Wlo + addr) = lv;
        }
        __syncthreads();

        short8v ahi[2], alo[2];
        #pragma unroll
        for (int ot = 0; ot < 2; ++ot) {
            int row = o0 + ot * 16 + c;
            int ao = row * 40 + (g ^ (row & 3)) * 8;
            ahi[ot] = *(const short8v*)(Whi + ao);
            alo[ot] = *(const short8v*)(Wlo + ao);
        }
        #pragma unroll
        for (int pt = 0; pt < 4; ++pt) {
            int row = pt * 16 + c;
            int bo = row * 40 + (g ^ ((row >> 3) & 3)) * 8;
            short8v bhi = *(const short8v*)(Xthi + bo);
            short8v blo = *(const short8v*)(Xtlo + bo);
            #pragma unroll
            for (int ot = 0; ot < 2; ++ot) {
                acc[ot][pt] = __builtin_amdgcn_mfma_f32_16x16x32_bf16(
                    ahi[ot], bhi, acc[ot][pt], 0, 0, 0);
                acc[ot][pt] = __builtin_amdgcn_mfma_f32_16x16x32_bf16(
                    ahi[ot], blo, acc[ot][pt], 0, 0, 0);
                acc[ot][pt] = __builtin_amdgcn_mfma_f32_16x16x32_bf16(
                    alo[ot], bhi, acc[ot][pt], 0, 0, 0);
                acc[ot][pt] = __builtin_amdgcn_mfma_f32_16x16x32_bf16(
                    alo[ot], blo, acc[ot][pt], 0, 0, 0);
            }
        }
        __syncthreads();
    }

    #pragma unroll
    for (int pt = 0; pt < 4; ++pt) {
        int px = pt * 16 + c;
        #pragma unroll
        for (int ot = 0; ot < 2; ++ot)
            #pragma unroll
            for (int r = 0; r < 4; ++r)
                x2t[o0 + ot * 16 + g * 4 + r][px] = lrelu(acc[ot][pt][r]);
    }
    #pragma unroll
    for (int p = 0; p < 4; ++p) {
        int lin = p * 1024 + tid * 4;
        int row = lin >> 7, kc = lin & 127;
        *(float4*)(&W31[row][kc]) = *(const float4*)(Wcl31 + row * 128 + kc);
    }
    __syncthreads();

    const int tcB = tid & 15;
    const int trB = tid >> 4;
    float accB[4][2];
    #pragma unroll
    for (int i = 0; i < 4; ++i)
        #pragma unroll
        for (int j = 0; j < 2; ++j)
            accB[i][j] = bcl31[trB * 2 + j];

    for (int k = 0; k < 128; ++k) {
        float4 a = *(const float4*)(&x2t[k][tcB * 4]);
        float av[4] = {a.x,a.y,a.z,a.w};
        float w0 = W31[trB * 2 + 0][k];
        float w1 = W31[trB * 2 + 1][k];
        #pragma unroll
        for (int i = 0; i < 4; ++i) {
            accB[i][0] = fmaf(av[i], w0, accB[i][0]);
            accB[i][1] = fmaf(av[i], w1, accB[i][1]);
        }
    }
    __syncthreads();

    #pragma unroll
    for (int i = 0; i < 4; ++i)
        #pragma unroll
        for (int j = 0; j < 2; ++j)
            cl1buf[tcB * 4 + i][trB * 2 + j] = accB[i][j];
    __syncthreads();
    if (tid < 64) {
        float bvv = cl1buf[tid][0]; int bi = 0;
        #pragma unroll
        for (int cc = 1; cc < 32; ++cc) {
            float v = cl1buf[tid][cc];
            if (v > bvv) { bvv = v; bi = cc; }
        }
        int n = n0 + tid;
        int ww = n / 192, hh = n - ww * 192;
        inds1_q[hh * 256 + ww] = bi;
    }
}

// ============================================================================
// k_hist / k_scanA / k_scatter2 (R0 text)
// ============================================================================
__global__ void k_hist(const int* __restrict__ inds1_q, int* __restrict__ bh) {
    int tid = threadIdx.x;
    int n = blockIdx.x * 256 + tid;
    int key = inds1_q[n];
    int lane = tid & 63;
    int cnt = 0;
    for (int k = 0; k < 32; ++k) {
        unsigned long long m = __ballot(key == k);
        if (lane == k) cnt = __popcll(m);
    }
    if (lane < 32) bh[(n >> 6) * 32 + lane] = cnt;
}

__global__ void k_scanA(const int* __restrict__ bh, int* __restrict__ ebb,
                        int* __restrict__ total) {
    __shared__ int s[256];
    const int k = blockIdx.x, t = threadIdx.x;
    int v0 = bh[(t * 3 + 0) * 32 + k];
    int v1 = bh[(t * 3 + 1) * 32 + k];
    int v2 = bh[(t * 3 + 2) * 32 + k];
    int sum = v0 + v1 + v2;
    s[t] = sum; __syncthreads();
    for (int d = 1; d < 256; d <<= 1) {
        int x = (t >= d) ? s[t - d] : 0;
        __syncthreads();
        s[t] += x;
        __syncthreads();
    }
    int ex = s[t] - sum;
    ebb[(t * 3 + 0) * 32 + k] = ex;
    ebb[(t * 3 + 1) * 32 + k] = ex + v0;
    ebb[(t * 3 + 2) * 32 + k] = ex + v0 + v1;
    if (t == 255) total[k] = s[255];
}

__global__ void k_scatter2(const int* __restrict__ inds1_q,
                           const int* __restrict__ ebb,
                           const int* __restrict__ total,
                           int* __restrict__ order)
{
    __shared__ int ttot[32];
    const int tid = threadIdx.x;
    if (tid < 32) ttot[tid] = total[tid];
    __syncthreads();
    int n = blockIdx.x * 256 + tid;
    int key = inds1_q[n];
    int lane = tid & 63;
    unsigned long long peers = 0;
    for (int k = 0; k < 32; ++k) {
        unsigned long long m = __ballot(key == k);
        if (key == k) peers = m;
    }
    int rank = __popcll(peers & ((1ull << lane) - 1ull));
    int cbase = 0;
    #pragma unroll
    for (int k = 0; k < 32; ++k) cbase += (k < key) ? ttot[k] : 0;
    order[cbase + ebb[(n >> 6) * 32 + key] + rank] = n;
}

// ============================================================================
// k2h: stage-2 first half (R0 text — CLOSED: R15/R17/R18 all regressed)
// ============================================================================
__global__ __launch_bounds__(256, 4) void k2h(
    const float* __restrict__ x_t,
    const float* __restrict__ Wcl22, const float* __restrict__ bcl22,
    const float* __restrict__ Wcl32, const float* __restrict__ bcl32,
    const int* __restrict__ total, const int* __restrict__ order,
    int* __restrict__ ind_ord)
{
    __shared__ float Was[4096];
    __shared__ float Wbs[1024];
    __shared__ int cpre[33];
    __shared__ int cbase[33];
    __shared__ int ttot[32];

    const int tid = threadIdx.x;
    if (tid < 32) ttot[tid] = total[tid];
    __syncthreads();
    if (tid == 0) {
        int s = 0, cb = 0;
        for (int k = 0; k < 32; ++k) {
            cpre[k] = s; cbase[k] = cb;
            int c = ttot[k];
            s += (c + 255) >> 8;
            cb += c;
        }
        cpre[32] = s; cbase[32] = cb;
    }
    __syncthreads();
    const int ci = blockIdx.x;
    if (ci >= cpre[32]) return;
    int cls = 0;
    while (cpre[cls + 1] <= ci) ++cls;
    const int st   = (ci - cpre[cls]) * 256;
    const int npx  = min(256, ttot[cls] - st);
    const int base = cbase[cls] + st;

    {
        const float4* ws = (const float4*)(Wcl22 + cls * 4096);
        #pragma unroll
        for (int j = 0; j < 4; ++j) ((float4*)Was)[j * 256 + tid] = ws[j * 256 + tid];
        ((float4*)Wbs)[tid] = ((const float4*)(Wcl32 + cls * 1024))[tid];
    }
    __syncthreads();

    const int m = order[base + min(tid, npx - 1)];
    const float4* xp = (const float4*)(x_t + (size_t)m * 128);

    float h[32];
    #pragma unroll
    for (int j = 0; j < 32; ++j) h[j] = bcl22[cls * 32 + j];
    #pragma unroll 2
    for (int c4 = 0; c4 < 32; ++c4) {
        float4 xv = xp[c4];
        float xa[4] = {xv.x, xv.y, xv.z, xv.w};
        #pragma unroll
        for (int cc = 0; cc < 4; ++cc) {
            const float* wr = &Was[(c4 * 4 + cc) * 32];
            #pragma unroll
            for (int j = 0; j < 32; ++j) h[j] = fmaf(xa[cc], wr[j], h[j]);
        }
    }
    #pragma unroll
    for (int j = 0; j < 32; ++j) h[j] = lrelu(h[j]);

    float g[32];
    #pragma unroll
    for (int j = 0; j < 32; ++j) g[j] = bcl32[cls * 32 + j];
    #pragma unroll 2
    for (int c = 0; c < 32; ++c) {
        float hv = h[c];
        const float* wr = &Wbs[c * 32];
        #pragma unroll
        for (int j = 0; j < 32; ++j) g[j] = fmaf(hv, wr[j], g[j]);
    }
    float bv = g[0]; int bi = 0;
    #pragma unroll
    for (int j = 1; j < 32; ++j)
        if (g[j] > bv) { bv = g[j]; bi = j; }     // strict > = first-max (np.argmax)
    if (tid < npx) ind_ord[base + tid] = cls * 32 + bi;
}

// ============================================================================
// k2r: stage-2 second half (R0 text)
// ============================================================================
__global__ __launch_bounds__(256, 4) void k2r(
    const float* __restrict__ r_t,
    const float* __restrict__ Wr2,  const float* __restrict__ br2,
    const float* __restrict__ Wr3,  const float* __restrict__ br3,
    const int* __restrict__ total, const int* __restrict__ order,
    const int* __restrict__ ind_ord,
    float* __restrict__ out)
{
    __shared__ float Wcs[4096];
    __shared__ int cpre[33];
    __shared__ int cbase[33];
    __shared__ int ttot[32];

    const int tid = threadIdx.x;
    if (tid < 32) ttot[tid] = total[tid];
    __syncthreads();
    if (tid == 0) {
        int s = 0, cb = 0;
        for (int k = 0; k < 32; ++k) {
            cpre[k] = s; cbase[k] = cb;
            int c = ttot[k];
            s += (c + 255) >> 8;
            cb += c;
        }
        cpre[32] = s; cbase[32] = cb;
    }
    __syncthreads();
    const int ci = blockIdx.x;
    if (ci >= cpre[32]) return;
    int cls = 0;
    while (cpre[cls + 1] <= ci) ++cls;
    const int st   = (ci - cpre[cls]) * 256;
    const int npx  = min(256, ttot[cls] - st);
    const int base = cbase[cls] + st;
    const int sup  = cls >> 2;

    {
        const float4* ws = (const float4*)(Wr2 + sup * 4096);
        #pragma unroll
        for (int j = 0; j < 4; ++j) ((float4*)Wcs)[j * 256 + tid] = ws[j * 256 + tid];
    }
    __syncthreads();

    const int li  = min(tid, npx - 1);
    const int m   = order[base + li];
    const int ind = ind_ord[base + li];
    const float4* rp = (const float4*)(r_t + (size_t)m * 128);

    float r2[32];
    #pragma unroll
    for (int j = 0; j < 32; ++j) r2[j] = br2[sup * 32 + j];
    #pragma unroll 2
    for (int c4 = 0; c4 < 32; ++c4) {
        float4 rv = rp[c4];
        float ra[4] = {rv.x, rv.y, rv.z, rv.w};
        #pragma unroll
        for (int cc = 0; cc < 4; ++cc) {
            const float* wr = &Wcs[(c4 * 4 + cc) * 32];
            #pragma unroll
            for (int j = 0; j < 32; ++j) r2[j] = fmaf(ra[cc], wr[j], r2[j]);
        }
    }

    float reg = br3[ind];
    const float* __restrict__ w3 = Wr3 + ind * 32;
    #pragma unroll
    for (int j = 0; j < 32; ++j) reg = fmaf(lrelu(r2[j]), w3[j], reg);

    if (tid < npx) out[m] = ((float)ind + reg) * (1.0f / 1024.0f);
}

extern "C" void kernel_launch(void* const* d_in, const int* in_sizes, int n_in,
                              void* d_out, int out_size, void* d_ws, size_t ws_size,
                              hipStream_t stream)
{
    const float* X     = (const float*)d_in[0];
    const float* Wm1   = (const float*)d_in[1];
    const float* bm1   = (const float*)d_in[2];
    const float* Wm2   = (const float*)d_in[3];
    const float* bm2   = (const float*)d_in[4];
    const float* Wm3   = (const float*)d_in[5];
    const float* bm3   = (const float*)d_in[6];
    const float* Wcl1  = (const float*)d_in[7];
    const float* bcl1  = (const float*)d_in[8];
    const float* Wcl21 = (const float*)d_in[9];
    const float* bcl21 = (const float*)d_in[10];
    const float* Wcl31 = (const float*)d_in[11];
    const float* bcl31 = (const float*)d_in[12];
    const float* Wcl22 = (const float*)d_in[13];
    const float* bcl22 = (const float*)d_in[14];
    const float* Wcl32 = (const float*)d_in[15];
    const float* bcl32 = (const float*)d_in[16];
    const float* Wr1   = (const float*)d_in[17];
    const float* br1   = (const float*)d_in[18];
    const float* Wr2   = (const float*)d_in[19];
    const float* br2   = (const float*)d_in[20];
    const float* Wr3   = (const float*)d_in[21];
    const float* br3   = (const float*)d_in[22];
    float* out = (float*)d_out;

    float* x_t   = (float*)d_ws;
    float* r_t   = x_t + (size_t)NPIX * 128;
    int* inds1_q = (int*)(r_t + (size_t)NPIX * 128);
    int* order   = inds1_q + NPIX;
    int* ind_ord = order + NPIX;
    int* bh      = ind_ord + NPIX;      // [768][32]
    int* ebb     = bh + NSEG * 32;      // [768][32]
    int* total   = ebb + NSEG * 32;     // [32]

    // y=0: merged x_t + r_t; y=1: mask
    k_fused1<<<dim3(NPIX / 128, 2), 256, 0, stream>>>(X, Wcl1, bcl1, Wr1, br1,
                                                      Wm1, bm1, Wm2, bm2, Wm3, bm3,
                                                      x_t, r_t, out);
    k1b<<<NPIX / 64, 256, 0, stream>>>(x_t, Wcl21, bcl21, Wcl31, bcl31, inds1_q);
    k_hist<<<NPIX / 256, 256, 0, stream>>>(inds1_q, bh);
    k_scanA<<<32, 256, 0, stream>>>(bh, ebb, total);
    k_scatter2<<<NPIX / 256, 256, 0, stream>>>(inds1_q, ebb, total, order);
    // 256-px chunks: worst case sum ceil = 192 + 31 = 223 -> grid 224 covers all
    k2h<<<224, 256, 0, stream>>>(x_t, Wcl22, bcl22, Wcl32, bcl32, total, order, ind_ord);
    k2r<<<224, 256, 0, stream>>>(r_t, Wr2, br2, Wr3, br3, total, order, ind_ord, out);
}

// Round 21
// 199.280 us; speedup vs baseline: 1.0137x; 1.0137x over previous
//
#include <hip/hip_runtime.h>

#define HH 192
#define WW 256
#define NPIX (HH*WW)   // 49152
#define NSEG (NPIX/64) // 768

__device__ __forceinline__ float lrelu(float v) { return v > 0.0f ? v : 0.01f * v; }

// bf16 hi/lo split helpers (RNE via round-half-up on guard bit)
__device__ __forceinline__ unsigned short bfhi(float x) {
    unsigned b = __float_as_uint(x);
    return (unsigned short)((b + 0x7FFFu + ((b >> 16) & 1u)) >> 16);
}
__device__ __forceinline__ float bff(unsigned short u) {
    return __uint_as_float(((unsigned)u) << 16);
}

typedef __attribute__((ext_vector_type(8))) short short8v;  // 8 bf16 = 4 VGPR
typedef __attribute__((ext_vector_type(4))) short short4v;  // 8B packed write
typedef __attribute__((ext_vector_type(4))) float f32x4;    // MFMA acc

// ============================================================================
// k_fused1 (R25/R24 text, verified 199.7us best): all branches bf16 hi/lo
// MFMA. y=1 3-term; y=2 3-term; y=0 4-term. absmax 2.441406e-4.
// R26 merge (y0+y1 shared staging) was NEUTRAL: FETCH 26->17MB but occupancy
// 24%->17% (2 blocks/CU at 60KB LDS) exactly offset the staging savings.
// Reverted. This is the committed floor configuration.
// ============================================================================
__global__ __launch_bounds__(256, 3) void k_fused1(
    const float* __restrict__ X,
    const float* __restrict__ Wcl1, const float* __restrict__ bcl1,
    const float* __restrict__ Wr1,  const float* __restrict__ br1,
    const float* __restrict__ Wm1,  const float* __restrict__ bm1,
    const float* __restrict__ Wm2,  const float* __restrict__ bm2,
    const float* __restrict__ Wm3,  const float* __restrict__ bm3,
    float* __restrict__ x_t, float* __restrict__ r_t,
    float* __restrict__ out)
{
    __shared__ float smem[10240];                      // 40960 B

    const int tid = threadIdx.x;
    const int q0  = blockIdx.x * 128;

    if (blockIdx.y == 2) {
        unsigned short* Wmhi = (unsigned short*)smem;          // [32][40]
        unsigned short* Wmlo = Wmhi + 1280;                    // [32][40]
        unsigned short* Xthi = Wmlo + 1280;                    // [128][40]
        unsigned short* Xtlo = Xthi + 5120;                    // [128][40]
        float (*m1b)[33] = (float(*)[33])smem;                 // post-loop alias

        const int l = tid & 63;
        const int w = tid >> 6;
        const int c = l & 15;
        const int g = l >> 4;

        float bvm[2][4];
        #pragma unroll
        for (int ot = 0; ot < 2; ++ot)
            #pragma unroll
            for (int r = 0; r < 4; ++r)
                bvm[ot][r] = bm1[ot * 16 + g * 4 + r];

        f32x4 accM[2][2];
        #pragma unroll
        for (int ot = 0; ot < 2; ++ot)
            #pragma unroll
            for (int pi = 0; pi < 2; ++pi) {
                accM[ot][pi][0] = bvm[ot][0]; accM[ot][pi][1] = bvm[ot][1];
                accM[ot][pi][2] = bvm[ot][2]; accM[ot][pi][3] = bvm[ot][3];
            }

        const int sx_px = tid & 127;
        const int sx_kh = (tid >> 7) * 16;
        const float* Xp = X + q0 + sx_px;

        for (int k0 = 0; k0 < 128; k0 += 32) {
            {
                float xv[16];
                #pragma unroll
                for (int i = 0; i < 16; ++i)
                    xv[i] = Xp[(size_t)(k0 + sx_kh + i) * NPIX];
                #pragma unroll
                for (int j = 0; j < 2; ++j) {
                    short8v hv, lv;
                    #pragma unroll
                    for (int i = 0; i < 8; ++i) {
                        unsigned short h = bfhi(xv[j * 8 + i]);
                        hv[i] = (short)h;
                        lv[i] = (short)bfhi(xv[j * 8 + i] - bff(h));
                    }
                    int gg = (sx_kh >> 3) + j;
                    int gs = gg ^ ((sx_px >> 3) & 3);
                    *(short8v*)(Xthi + sx_px * 40 + gs * 8) = hv;
                    *(short8v*)(Xtlo + sx_px * 40 + gs * 8) = lv;
                }
            }
            {
                int o = tid >> 3, kc = (tid & 7) * 4;
                float4 v = *(const float4*)(Wm1 + o * 128 + k0 + kc);
                float wv[4] = {v.x, v.y, v.z, v.w};
                short4v hv, lv;
                #pragma unroll
                for (int i = 0; i < 4; ++i) {
                    unsigned short h = bfhi(wv[i]);
                    hv[i] = (short)h;
                    lv[i] = (short)bfhi(wv[i] - bff(h));
                }
                int gg = kc >> 3;
                int gs = gg ^ (o & 3);
                int addr = o * 40 + gs * 8 + (kc & 7);
                *(short4v*)(Wmhi + addr) = hv;
                *(short4v*)(Wmlo + addr) = lv;
            }
            __syncthreads();

            short8v ahi[2], alo[2];
            #pragma unroll
            for (int ot = 0; ot < 2; ++ot) {
                int row = ot * 16 + c;
                int ao = row * 40 + (g ^ (row & 3)) * 8;
                ahi[ot] = *(const short8v*)(Wmhi + ao);
                alo[ot] = *(const short8v*)(Wmlo + ao);
            }
            #pragma unroll
            for (int pi = 0; pi < 2; ++pi) {
                int row = (2 * w + pi) * 16 + c;
                int bo = row * 40 + (g ^ ((row >> 3) & 3)) * 8;
                short8v bhi = *(const short8v*)(Xthi + bo);
                short8v blo = *(const short8v*)(Xtlo + bo);
                #pragma unroll
                for (int ot = 0; ot < 2; ++ot) {
                    accM[ot][pi] = __builtin_amdgcn_mfma_f32_16x16x32_bf16(
                        ahi[ot], bhi, accM[ot][pi], 0, 0, 0);
                    accM[ot][pi] = __builtin_amdgcn_mfma_f32_16x16x32_bf16(
                        ahi[ot], blo, accM[ot][pi], 0, 0, 0);
                    accM[ot][pi] = __builtin_amdgcn_mfma_f32_16x16x32_bf16(
                        alo[ot], bhi, accM[ot][pi], 0, 0, 0);
                }
            }
            __syncthreads();
        }
        #pragma unroll
        for (int pi = 0; pi < 2; ++pi) {
            int px = (2 * w + pi) * 16 + c;
            #pragma unroll
            for (int ot = 0; ot < 2; ++ot)
                #pragma unroll
                for (int r = 0; r < 4; ++r)
                    m1b[px][ot * 16 + g * 4 + r] = lrelu(accM[ot][pi][r]);
        }
        __syncthreads();
        if (tid < 128) {
            float m3 = bm3[0];
            #pragma unroll 2
            for (int j = 0; j < 16; ++j) {
                float s = bm2[j];
                #pragma unroll
                for (int k = 0; k < 32; ++k)
                    s = fmaf(Wm2[j * 32 + k], m1b[tid][k], s);
                m3 = fmaf(Wm3[j], lrelu(s), m3);
            }
            out[NPIX + q0 + tid] = lrelu(m3);
        }
        return;
    }

    // ---- y=0 / y=1: x_t (4-term) / r_t (3-term) via bf16 hi/lo MFMA ----
    {
        const bool exact = (blockIdx.y == 0);   // y0: add Wlo.Xlo term
        const float* __restrict__ Wsrc = exact ? Wcl1 : Wr1;
        const float* __restrict__ bsrc = exact ? bcl1 : br1;
        float* __restrict__ osrc       = exact ? x_t : r_t;

        unsigned short* Whi  = (unsigned short*)smem;            // [128][40]
        unsigned short* Wlo  = Whi  + 5120;                      // [128][40]
        unsigned short* Xthi = Wlo  + 5120;                      // [128px][40]
        unsigned short* Xtlo = Xthi + 5120;                      // [128px][40]

        const int l = tid & 63;
        const int w = tid >> 6;
        const int c = l & 15;
        const int g = l >> 4;
        const int o0 = w * 32;

        float bv[2][4];
        #pragma unroll
        for (int ot = 0; ot < 2; ++ot)
            #pragma unroll
            for (int r = 0; r < 4; ++r)
                bv[ot][r] = bsrc[o0 + ot * 16 + g * 4 + r];

        f32x4 acc[2][8];
        #pragma unroll
        for (int ot = 0; ot < 2; ++ot)
            #pragma unroll
            for (int pt = 0; pt < 8; ++pt) {
                acc[ot][pt][0] = bv[ot][0]; acc[ot][pt][1] = bv[ot][1];
                acc[ot][pt][2] = bv[ot][2]; acc[ot][pt][3] = bv[ot][3];
            }

        const int sx_px = tid & 127;
        const int sx_kh = (tid >> 7) * 16;
        const float* Xp = X + q0 + sx_px;

        for (int k0 = 0; k0 < 128; k0 += 32) {
            {
                float xv[16];
                #pragma unroll
                for (int i = 0; i < 16; ++i)
                    xv[i] = Xp[(size_t)(k0 + sx_kh + i) * NPIX];
                #pragma unroll
                for (int j = 0; j < 2; ++j) {
                    short8v hv, lv;
                    #pragma unroll
                    for (int i = 0; i < 8; ++i) {
                        unsigned short h = bfhi(xv[j * 8 + i]);
                        hv[i] = (short)h;
                        lv[i] = (short)bfhi(xv[j * 8 + i] - bff(h));
                    }
                    int gg = (sx_kh >> 3) + j;
                    int gs = gg ^ ((sx_px >> 3) & 3);
                    *(short8v*)(Xthi + sx_px * 40 + gs * 8) = hv;
                    *(short8v*)(Xtlo + sx_px * 40 + gs * 8) = lv;
                }
            }
            #pragma unroll
            for (int p = 0; p < 4; ++p) {
                int lin = p * 1024 + tid * 4;
                int o = lin >> 5, kc = lin & 31;
                float4 v = *(const float4*)(Wsrc + o * 128 + k0 + kc);
                float wv[4] = {v.x, v.y, v.z, v.w};
                short4v hv, lv;
                #pragma unroll
                for (int i = 0; i < 4; ++i) {
                    unsigned short h = bfhi(wv[i]);
                    hv[i] = (short)h;
                    lv[i] = (short)bfhi(wv[i] - bff(h));
                }
                int gg = kc >> 3;
                int gs = gg ^ (o & 3);
                int addr = o * 40 + gs * 8 + (kc & 7);
                *(short4v*)(Whi + addr) = hv;
                *(short4v*)(Wlo + addr) = lv;
            }
            __syncthreads();

            short8v ahi[2], alo[2];
            #pragma unroll
            for (int ot = 0; ot < 2; ++ot) {
                int row = o0 + ot * 16 + c;
                int ao = row * 40 + (g ^ (row & 3)) * 8;
                ahi[ot] = *(const short8v*)(Whi + ao);
                alo[ot] = *(const short8v*)(Wlo + ao);
            }
            #pragma unroll
            for (int pt = 0; pt < 8; ++pt) {
                int row = pt * 16 + c;
                int bo = row * 40 + (g ^ ((row >> 3) & 3)) * 8;
                short8v bhi = *(const short8v*)(Xthi + bo);
                short8v blo = *(const short8v*)(Xtlo + bo);
                #pragma unroll
                for (int ot = 0; ot < 2; ++ot) {
                    acc[ot][pt] = __builtin_amdgcn_mfma_f32_16x16x32_bf16(
                        ahi[ot], bhi, acc[ot][pt], 0, 0, 0);
                    acc[ot][pt] = __builtin_amdgcn_mfma_f32_16x16x32_bf16(
                        ahi[ot], blo, acc[ot][pt], 0, 0, 0);
                    acc[ot][pt] = __builtin_amdgcn_mfma_f32_16x16x32_bf16(
                        alo[ot], bhi, acc[ot][pt], 0, 0, 0);
                    if (exact)
                        acc[ot][pt] = __builtin_amdgcn_mfma_f32_16x16x32_bf16(
                            alo[ot], blo, acc[ot][pt], 0, 0, 0);
                }
            }
            __syncthreads();
        }

        #pragma unroll
        for (int pt = 0; pt < 8; ++pt) {
            int px = pt * 16 + c;
            int q  = q0 + px;
            int np = (q & 255) * 192 + (q >> 8);
            float* op = osrc + (size_t)np * 128;
            #pragma unroll
            for (int ot = 0; ot < 2; ++ot) {
                float4 o4;
                o4.x = lrelu(acc[ot][pt][0]); o4.y = lrelu(acc[ot][pt][1]);
                o4.z = lrelu(acc[ot][pt][2]); o4.w = lrelu(acc[ot][pt][3]);
                *(float4*)(op + o0 + ot * 16 + g * 4) = o4;
            }
        }
    }
}

// ============================================================================
// k1b (R25 text, verified): 4-term MFMA GEMM + fp32 B-phase, PX=64.
// ============================================================================
__global__ __launch_bounds__(256, 3) void k1b(
    const float* __restrict__ x_t,
    const float* __restrict__ Wcl21, const float* __restrict__ bcl21,
    const float* __restrict__ Wcl31, const float* __restrict__ bcl31,
    int* __restrict__ inds1_q)
{
    __shared__ float smem[12928];                       // 51712 B
    unsigned short* Whi  = (unsigned short*)smem;       // [128][40]
    unsigned short* Wlo  = Whi + 5120;                  // [128][40]
    unsigned short* Xthi = Wlo + 5120;                  // [64][40]
    unsigned short* Xtlo = Xthi + 2560;                 // [64][40]
    float (*x2t)[68]    = (float(*)[68])smem;           // [128][68]
    float (*W31)[132]   = (float(*)[132])(smem + 8704); // [32][132]
    float (*cl1buf)[33] = (float(*)[33])(smem + 8704);  // aliases W31

    const int tid = threadIdx.x;
    const int n0  = blockIdx.x * 64;
    const int l = tid & 63, w = tid >> 6;
    const int c = l & 15, g = l >> 4;
    const int o0 = w * 32;

    float bv[2][4];
    #pragma unroll
    for (int ot = 0; ot < 2; ++ot)
        #pragma unroll
        for (int r = 0; r < 4; ++r)
            bv[ot][r] = bcl21[o0 + ot * 16 + g * 4 + r];

    f32x4 acc[2][4];
    #pragma unroll
    for (int ot = 0; ot < 2; ++ot)
        #pragma unroll
        for (int pt = 0; pt < 4; ++pt) {
            acc[ot][pt][0] = bv[ot][0]; acc[ot][pt][1] = bv[ot][1];
            acc[ot][pt][2] = bv[ot][2]; acc[ot][pt][3] = bv[ot][3];
        }

    const int sx_px = tid & 63;
    const int sx_kh = (tid >> 6) * 8;
    const float* Xp = x_t + (size_t)(n0 + sx_px) * 128 + sx_kh;

    for (int k0 = 0; k0 < 128; k0 += 32) {
        {
            float4 v0 = *(const float4*)(Xp + k0);
            float4 v1 = *(const float4*)(Xp + k0 + 4);
            float xv[8] = {v0.x,v0.y,v0.z,v0.w,v1.x,v1.y,v1.z,v1.w};
            short8v hv, lv;
            #pragma unroll
            for (int i = 0; i < 8; ++i) {
                unsigned short h = bfhi(xv[i]);
                hv[i] = (short)h;
                lv[i] = (short)bfhi(xv[i] - bff(h));
            }
            int gg = sx_kh >> 3;
            int gs = gg ^ ((sx_px >> 3) & 3);
            *(short8v*)(Xthi + sx_px * 40 + gs * 8) = hv;
            *(short8v*)(Xtlo + sx_px * 40 + gs * 8) = lv;
        }
        #pragma unroll
        for (int p = 0; p < 4; ++p) {
            int lin = p * 1024 + tid * 4;
            int o = lin >> 5, kc = lin & 31;
            float4 v = *(const float4*)(Wcl21 + o * 128 + k0 + kc);
            float wv[4] = {v.x, v.y, v.z, v.w};
            short4v hv, lv;
            #pragma unroll
            for (int i = 0; i < 4; ++i) {
                unsigned short h = bfhi(wv[i]);
                hv[i] = (short)h;
                lv[i] = (short)bfhi(wv[i] - bff(h));
            }
            int gg = kc >> 3;
            int gs = gg ^ (o & 3);
            int addr = o * 40 + gs * 8 + (kc & 7);
            *(short4v*)(Whi + addr) = hv;
            *(short4v*)(Wlo + addr) = lv;
        }
        __syncthreads();

        short8v ahi[2], alo[2];
        #pragma unroll
        for (int ot = 0; ot < 2; ++ot) {
            int row = o0 + ot * 16 + c;
            int ao = row * 40 + (g ^ (row & 3)) * 8;
            ahi[ot] = *(const short8v*)(Whi + ao);
            alo[ot] = *(const short8v*)(Wlo + ao);
        }
        #pragma unroll
        for (int pt = 0; pt < 4; ++pt) {
            int row = pt * 16 + c;
            int bo = row * 40 + (g ^ ((row >> 3) & 3)) * 8;
            short8v bhi = *(const short8v*)(Xthi + bo);
            short8v blo = *(const short8v*)(Xtlo + bo);
            #pragma unroll
            for (int ot = 0; ot < 2; ++ot) {
                acc[ot][pt] = __builtin_amdgcn_mfma_f32_16x16x32_bf16(
                    ahi[ot], bhi, acc[ot][pt], 0, 0, 0);
                acc[ot][pt] = __builtin_amdgcn_mfma_f32_16x16x32_bf16(
                    ahi[ot], blo, acc[ot][pt], 0, 0, 0);
                acc[ot][pt] = __builtin_amdgcn_mfma_f32_16x16x32_bf16(
                    alo[ot], bhi, acc[ot][pt], 0, 0, 0);
                acc[ot][pt] = __builtin_amdgcn_mfma_f32_16x16x32_bf16(
                    alo[ot], blo, acc[ot][pt], 0, 0, 0);
            }
        }
        __syncthreads();
    }

    #pragma unroll
    for (int pt = 0; pt < 4; ++pt) {
        int px = pt * 16 + c;
        #pragma unroll
        for (int ot = 0; ot < 2; ++ot)
            #pragma unroll
            for (int r = 0; r < 4; ++r)
                x2t[o0 + ot * 16 + g * 4 + r][px] = lrelu(acc[ot][pt][r]);
    }
    #pragma unroll
    for (int p = 0; p < 4; ++p) {
        int lin = p * 1024 + tid * 4;
        int row = lin >> 7, kc = lin & 127;
        *(float4*)(&W31[row][kc]) = *(const float4*)(Wcl31 + row * 128 + kc);
    }
    __syncthreads();

    const int tcB = tid & 15;
    const int trB = tid >> 4;
    float accB[4][2];
    #pragma unroll
    for (int i = 0; i < 4; ++i)
        #pragma unroll
        for (int j = 0; j < 2; ++j)
            accB[i][j] = bcl31[trB * 2 + j];

    for (int k = 0; k < 128; ++k) {
        float4 a = *(const float4*)(&x2t[k][tcB * 4]);
        float av[4] = {a.x,a.y,a.z,a.w};
        float w0 = W31[trB * 2 + 0][k];
        float w1 = W31[trB * 2 + 1][k];
        #pragma unroll
        for (int i = 0; i < 4; ++i) {
            accB[i][0] = fmaf(av[i], w0, accB[i][0]);
            accB[i][1] = fmaf(av[i], w1, accB[i][1]);
        }
    }
    __syncthreads();

    #pragma unroll
    for (int i = 0; i < 4; ++i)
        #pragma unroll
        for (int j = 0; j < 2; ++j)
            cl1buf[tcB * 4 + i][trB * 2 + j] = accB[i][j];
    __syncthreads();
    if (tid < 64) {
        float bvv = cl1buf[tid][0]; int bi = 0;
        #pragma unroll
        for (int cc = 1; cc < 32; ++cc) {
            float v = cl1buf[tid][cc];
            if (v > bvv) { bvv = v; bi = cc; }
        }
        int n = n0 + tid;
        int ww = n / 192, hh = n - ww * 192;
        inds1_q[hh * 256 + ww] = bi;
    }
}

// ============================================================================
// k_hist / k_scanA / k_scatter2 (R0 text)
// ============================================================================
__global__ void k_hist(const int* __restrict__ inds1_q, int* __restrict__ bh) {
    int tid = threadIdx.x;
    int n = blockIdx.x * 256 + tid;
    int key = inds1_q[n];
    int lane = tid & 63;
    int cnt = 0;
    for (int k = 0; k < 32; ++k) {
        unsigned long long m = __ballot(key == k);
        if (lane == k) cnt = __popcll(m);
    }
    if (lane < 32) bh[(n >> 6) * 32 + lane] = cnt;
}

__global__ void k_scanA(const int* __restrict__ bh, int* __restrict__ ebb,
                        int* __restrict__ total) {
    __shared__ int s[256];
    const int k = blockIdx.x, t = threadIdx.x;
    int v0 = bh[(t * 3 + 0) * 32 + k];
    int v1 = bh[(t * 3 + 1) * 32 + k];
    int v2 = bh[(t * 3 + 2) * 32 + k];
    int sum = v0 + v1 + v2;
    s[t] = sum; __syncthreads();
    for (int d = 1; d < 256; d <<= 1) {
        int x = (t >= d) ? s[t - d] : 0;
        __syncthreads();
        s[t] += x;
        __syncthreads();
    }
    int ex = s[t] - sum;
    ebb[(t * 3 + 0) * 32 + k] = ex;
    ebb[(t * 3 + 1) * 32 + k] = ex + v0;
    ebb[(t * 3 + 2) * 32 + k] = ex + v0 + v1;
    if (t == 255) total[k] = s[255];
}

__global__ void k_scatter2(const int* __restrict__ inds1_q,
                           const int* __restrict__ ebb,
                           const int* __restrict__ total,
                           int* __restrict__ order)
{
    __shared__ int ttot[32];
    const int tid = threadIdx.x;
    if (tid < 32) ttot[tid] = total[tid];
    __syncthreads();
    int n = blockIdx.x * 256 + tid;
    int key = inds1_q[n];
    int lane = tid & 63;
    unsigned long long peers = 0;
    for (int k = 0; k < 32; ++k) {
        unsigned long long m = __ballot(key == k);
        if (key == k) peers = m;
    }
    int rank = __popcll(peers & ((1ull << lane) - 1ull));
    int cbase = 0;
    #pragma unroll
    for (int k = 0; k < 32; ++k) cbase += (k < key) ? ttot[k] : 0;
    order[cbase + ebb[(n >> 6) * 32 + key] + rank] = n;
}

// ============================================================================
// k2h: stage-2 first half (R0 text)
// ============================================================================
__global__ __launch_bounds__(256, 4) void k2h(
    const float* __restrict__ x_t,
    const float* __restrict__ Wcl22, const float* __restrict__ bcl22,
    const float* __restrict__ Wcl32, const float* __restrict__ bcl32,
    const int* __restrict__ total, const int* __restrict__ order,
    int* __restrict__ ind_ord)
{
    __shared__ float Was[4096];
    __shared__ float Wbs[1024];
    __shared__ int cpre[33];
    __shared__ int cbase[33];
    __shared__ int ttot[32];

    const int tid = threadIdx.x;
    if (tid < 32) ttot[tid] = total[tid];
    __syncthreads();
    if (tid == 0) {
        int s = 0, cb = 0;
        for (int k = 0; k < 32; ++k) {
            cpre[k] = s; cbase[k] = cb;
            int c = ttot[k];
            s += (c + 255) >> 8;
            cb += c;
        }
        cpre[32] = s; cbase[32] = cb;
    }
    __syncthreads();
    const int ci = blockIdx.x;
    if (ci >= cpre[32]) return;
    int cls = 0;
    while (cpre[cls + 1] <= ci) ++cls;
    const int st   = (ci - cpre[cls]) * 256;
    const int npx  = min(256, ttot[cls] - st);
    const int base = cbase[cls] + st;

    {
        const float4* ws = (const float4*)(Wcl22 + cls * 4096);
        #pragma unroll
        for (int j = 0; j < 4; ++j) ((float4*)Was)[j * 256 + tid] = ws[j * 256 + tid];
        ((float4*)Wbs)[tid] = ((const float4*)(Wcl32 + cls * 1024))[tid];
    }
    __syncthreads();

    const int m = order[base + min(tid, npx - 1)];
    const float4* xp = (const float4*)(x_t + (size_t)m * 128);

    float h[32];
    #pragma unroll
    for (int j = 0; j < 32; ++j) h[j] = bcl22[cls * 32 + j];
    #pragma unroll 2
    for (int c4 = 0; c4 < 32; ++c4) {
        float4 xv = xp[c4];
        float xa[4] = {xv.x, xv.y, xv.z, xv.w};
        #pragma unroll
        for (int cc = 0; cc < 4; ++cc) {
            const float* wr = &Was[(c4 * 4 + cc) * 32];
            #pragma unroll
            for (int j = 0; j < 32; ++j) h[j] = fmaf(xa[cc], wr[j], h[j]);
        }
    }
    #pragma unroll
    for (int j = 0; j < 32; ++j) h[j] = lrelu(h[j]);

    float g[32];
    #pragma unroll
    for (int j = 0; j < 32; ++j) g[j] = bcl32[cls * 32 + j];
    #pragma unroll 2
    for (int c = 0; c < 32; ++c) {
        float hv = h[c];
        const float* wr = &Wbs[c * 32];
        #pragma unroll
        for (int j = 0; j < 32; ++j) g[j] = fmaf(hv, wr[j], g[j]);
    }
    float bv = g[0]; int bi = 0;
    #pragma unroll
    for (int j = 1; j < 32; ++j)
        if (g[j] > bv) { bv = g[j]; bi = j; }     // strict > = first-max (np.argmax)
    if (tid < npx) ind_ord[base + tid] = cls * 32 + bi;
}

// ============================================================================
// k2r: stage-2 second half (R0 text)
// ============================================================================
__global__ __launch_bounds__(256, 4) void k2r(
    const float* __restrict__ r_t,
    const float* __restrict__ Wr2,  const float* __restrict__ br2,
    const float* __restrict__ Wr3,  const float* __restrict__ br3,
    const int* __restrict__ total, const int* __restrict__ order,
    const int* __restrict__ ind_ord,
    float* __restrict__ out)
{
    __shared__ float Wcs[4096];
    __shared__ int cpre[33];
    __shared__ int cbase[33];
    __shared__ int ttot[32];

    const int tid = threadIdx.x;
    if (tid < 32) ttot[tid] = total[tid];
    __syncthreads();
    if (tid == 0) {
        int s = 0, cb = 0;
        for (int k = 0; k < 32; ++k) {
            cpre[k] = s; cbase[k] = cb;
            int c = ttot[k];
            s += (c + 255) >> 8;
            cb += c;
        }
        cpre[32] = s; cbase[32] = cb;
    }
    __syncthreads();
    const int ci = blockIdx.x;
    if (ci >= cpre[32]) return;
    int cls = 0;
    while (cpre[cls + 1] <= ci) ++cls;
    const int st   = (ci - cpre[cls]) * 256;
    const int npx  = min(256, ttot[cls] - st);
    const int base = cbase[cls] + st;
    const int sup  = cls >> 2;

    {
        const float4* ws = (const float4*)(Wr2 + sup * 4096);
        #pragma unroll
        for (int j = 0; j < 4; ++j) ((float4*)Wcs)[j * 256 + tid] = ws[j * 256 + tid];
    }
    __syncthreads();

    const int li  = min(tid, npx - 1);
    const int m   = order[base + li];
    const int ind = ind_ord[base + li];
    const float4* rp = (const float4*)(r_t + (size_t)m * 128);

    float r2[32];
    #pragma unroll
    for (int j = 0; j < 32; ++j) r2[j] = br2[sup * 32 + j];
    #pragma unroll 2
    for (int c4 = 0; c4 < 32; ++c4) {
        float4 rv = rp[c4];
        float ra[4] = {rv.x, rv.y, rv.z, rv.w};
        #pragma unroll
        for (int cc = 0; cc < 4; ++cc) {
            const float* wr = &Wcs[(c4 * 4 + cc) * 32];
            #pragma unroll
            for (int j = 0; j < 32; ++j) r2[j] = fmaf(ra[cc], wr[j], r2[j]);
        }
    }

    float reg = br3[ind];
    const float* __restrict__ w3 = Wr3 + ind * 32;
    #pragma unroll
    for (int j = 0; j < 32; ++j) reg = fmaf(lrelu(r2[j]), w3[j], reg);

    if (tid < npx) out[m] = ((float)ind + reg) * (1.0f / 1024.0f);
}

extern "C" void kernel_launch(void* const* d_in, const int* in_sizes, int n_in,
                              void* d_out, int out_size, void* d_ws, size_t ws_size,
                              hipStream_t stream)
{
    const float* X     = (const float*)d_in[0];
    const float* Wm1   = (const float*)d_in[1];
    const float* bm1   = (const float*)d_in[2];
    const float* Wm2   = (const float*)d_in[3];
    const float* bm2   = (const float*)d_in[4];
    const float* Wm3   = (const float*)d_in[5];
    const float* bm3   = (const float*)d_in[6];
    const float* Wcl1  = (const float*)d_in[7];
    const float* bcl1  = (const float*)d_in[8];
    const float* Wcl21 = (const float*)d_in[9];
    const float* bcl21 = (const float*)d_in[10];
    const float* Wcl31 = (const float*)d_in[11];
    const float* bcl31 = (const float*)d_in[12];
    const float* Wcl22 = (const float*)d_in[13];
    const float* bcl22 = (const float*)d_in[14];
    const float* Wcl32 = (const float*)d_in[15];
    const float* bcl32 = (const float*)d_in[16];
    const float* Wr1   = (const float*)d_in[17];
    const float* br1   = (const float*)d_in[18];
    const float* Wr2   = (const float*)d_in[19];
    const float* br2   = (const float*)d_in[20];
    const float* Wr3   = (const float*)d_in[21];
    const float* br3   = (const float*)d_in[22];
    float* out = (float*)d_out;

    float* x_t   = (float*)d_ws;
    float* r_t   = x_t + (size_t)NPIX * 128;
    int* inds1_q = (int*)(r_t + (size_t)NPIX * 128);
    int* order   = inds1_q + NPIX;
    int* ind_ord = order + NPIX;
    int* bh      = ind_ord + NPIX;      // [768][32]
    int* ebb     = bh + NSEG * 32;      // [768][32]
    int* total   = ebb + NSEG * 32;     // [32]

    k_fused1<<<dim3(NPIX / 128, 3), 256, 0, stream>>>(X, Wcl1, bcl1, Wr1, br1,
                                                      Wm1, bm1, Wm2, bm2, Wm3, bm3,
                                                      x_t, r_t, out);
    k1b<<<NPIX / 64, 256, 0, stream>>>(x_t, Wcl21, bcl21, Wcl31, bcl31, inds1_q);
    k_hist<<<NPIX / 256, 256, 0, stream>>>(inds1_q, bh);
    k_scanA<<<32, 256, 0, stream>>>(bh, ebb, total);
    k_scatter2<<<NPIX / 256, 256, 0, stream>>>(inds1_q, ebb, total, order);
    // 256-px chunks: worst case sum ceil = 192 + 31 = 223 -> grid 224 covers all
    k2h<<<224, 256, 0, stream>>>(x_t, Wcl22, bcl22, Wcl32, bcl32, total, order, ind_ord);
    k2r<<<224, 256, 0, stream>>>(r_t, Wr2, br2, Wr3, br3, total, order, ind_ord, out);
}